// Round 6
// baseline (516.145 us; speedup 1.0000x reference)
//
#include <hip/hip_runtime.h>
#include <hip/hip_bf16.h>
#include <math.h>

// Problem constants
#define MTOK 16384   // B*N tokens
#define DDIM 1024
#define EEXP 8
#define FDIM 512
#define EFK  4096    // E*F flattened K for second GEMM

typedef __attribute__((ext_vector_type(8))) short short8;   // 8 bf16 = 4 VGPRs (MFMA A/B frag)
typedef __attribute__((ext_vector_type(4))) float floatx4;  // MFMA C/D frag

__device__ __forceinline__ void gld_lds16(const void* g, void* l) {
  // async global->LDS, 16B per lane, dest = wave-uniform base + lane*16
  __builtin_amdgcn_global_load_lds((const __attribute__((address_space(1))) void*)g,
                                   (__attribute__((address_space(3))) void*)l, 16, 0, 0);
}

// Fast exact-GELU via Abramowitz-Stegun 7.1.26 erf approx (|eps| <= 1.5e-7).
__device__ __forceinline__ float gelu_fast(float v) {
  const float z  = v * 0.70710678118654752f;
  const float az = fabsf(z);
  const float t  = __builtin_amdgcn_rcpf(1.f + 0.3275911f * az);
  const float poly = t * (0.254829592f +
                     t * (-0.284496736f +
                     t * (1.421413741f +
                     t * (-1.453152027f +
                     t * 1.061405429f))));
  const float ex = __expf(-az * az);
  float erfv = 1.f - poly * ex;
  erfv = copysignf(erfv, z);
  return 0.5f * v * (1.f + erfv);
}

// ============================================================================
// Fragment-order weight producers. A-frag for v_mfma_f32_16x16x32_bf16:
// lane l = q*16 + m  (m = l&15, q = l>>4) holds row m, k = q*8 .. q*8+7 of a
// 16-row x 32-k fragment. This lane mapping is copied from the VERIFIED LDS
// read path of R1-R5 (refcheck-passed): lane(lanem, laneq) <- G[row=..+lanem]
// [k = kblock*32 + laneq*8 + 0..7]. One wave emits one 1 KiB fragment.
// ============================================================================

// W2 [EFK][D] f32 -> W2f frags [kb 0..127][mf 0..63] x 1024 B
__global__ __launch_bounds__(256) void frag_cast_w2(
    const float* __restrict__ W2, __hip_bfloat16* __restrict__ W2f) {
  const int gid  = blockIdx.x * 4 + (threadIdx.x >> 6);   // frag id, 8192 total
  const int lane = threadIdx.x & 63;
  const int kb = gid >> 6, mf = gid & 63;
  const int d  = mf * 16 + (lane & 15);
  const int k0 = kb * 32 + (lane >> 4) * 8;
  union { short8 v; __hip_bfloat16 h[8]; } pk;
#pragma unroll
  for (int i = 0; i < 8; ++i)
    pk.h[i] = __float2bfloat16(W2[(size_t)(k0 + i) * DDIM + d]);
  *(short8*)((char*)W2f + (size_t)gid * 1024 + lane * 16) = pk.v;
}

// W1 [E][D][F] f32 -> W1f frags [e][kb 0..31][mf 0..31] x 1024 B
__global__ __launch_bounds__(256) void frag_cast_w1(
    const float* __restrict__ W1, __hip_bfloat16* __restrict__ W1f) {
  const int gid  = blockIdx.x * 4 + (threadIdx.x >> 6);   // frag id, 8192 total
  const int lane = threadIdx.x & 63;
  const int e = gid >> 10, kb = (gid >> 5) & 31, mf = gid & 31;
  const int f  = mf * 16 + (lane & 15);
  const int d0 = kb * 32 + (lane >> 4) * 8;
  union { short8 v; __hip_bfloat16 h[8]; } pk;
#pragma unroll
  for (int i = 0; i < 8; ++i)
    pk.h[i] = __float2bfloat16(W1[((size_t)e * DDIM + d0 + i) * FDIM + f]);
  *(short8*)((char*)W1f + (size_t)gid * 1024 + lane * 16) = pk.v;
}

// ---------------- router softmax (fp32) + x -> bf16 cast. One wave per token.
__global__ __launch_bounds__(256) void router_cast_kernel(
    const float* __restrict__ x, const float* __restrict__ Wr, const float* __restrict__ br,
    __hip_bfloat16* __restrict__ xbf, float* __restrict__ r) {
  const int wave = (blockIdx.x * 256 + threadIdx.x) >> 6;  // token id
  const int lane = threadIdx.x & 63;
  const float* xr = x + (size_t)wave * DDIM;
  float acc[EEXP];
#pragma unroll
  for (int e = 0; e < EEXP; ++e) acc[e] = 0.f;
#pragma unroll
  for (int i = 0; i < DDIM / 64; ++i) {
    const int d = i * 64 + lane;
    const float xv = xr[d];
    xbf[(size_t)wave * DDIM + d] = __float2bfloat16(xv);
    const float4* w4 = (const float4*)(Wr + (size_t)d * EEXP);
    const float4 w0 = w4[0], w1 = w4[1];
    acc[0] += xv * w0.x; acc[1] += xv * w0.y; acc[2] += xv * w0.z; acc[3] += xv * w0.w;
    acc[4] += xv * w1.x; acc[5] += xv * w1.y; acc[6] += xv * w1.z; acc[7] += xv * w1.w;
  }
#pragma unroll
  for (int off = 32; off; off >>= 1) {
#pragma unroll
    for (int e = 0; e < EEXP; ++e) acc[e] += __shfl_xor(acc[e], off, 64);
  }
  float mx = -1e30f;
#pragma unroll
  for (int e = 0; e < EEXP; ++e) { acc[e] += br[e]; mx = fmaxf(mx, acc[e]); }
  float s = 0.f;
#pragma unroll
  for (int e = 0; e < EEXP; ++e) { acc[e] = expf(acc[e] - mx); s += acc[e]; }
  const float inv = 1.f / s;
  if (lane < EEXP) r[(size_t)wave * EEXP + lane] = acc[lane] * inv;
}

// ============================================================================
// R6 core: A (weights) DIRECT FROM GLOBAL in fragment order (no LDS), B
// (tokens) via gld_lds + XOR-swizzled LDS (the R1-verified 0-conflict path).
//
// R1-R5 post-mortem: five different schedules all ~6800 cyc/K-tile because
// per-CU per-tile LDS traffic (192 KB reads + 64 KB DMA writes) ~ MFMA time
// and the two refuse to overlap. Fix = remove 2/3 of LDS traffic: A-frags are
// single coalesced global_load_dwordx4 per lane (frag-ordered weights, built
// by frag_cast_*), shared by the 4 same-wr waves via L1 (16 KB set). LDS keeps
// only B: 96 KB/tile.
//
// Per K-tile t (B buf p = t&1): one fused "vmcnt(16); s_barrier" (counted —
// A-loads stay in flight across the barrier), stage B(t+1) [4 gld_lds,
// issue-pinned first by sched_barrier(0)], read bf [8 ds_read_b128], then
// {MFMA32(afk0) ; LOAD_A8(afk0 <- t+1,kb0)} {MFMA32(afk1) ; LOAD_A8(afk1 <-
// t+1,kb1)} — each A bank reloaded right after its last use (no tile-parity
// dbuf -> fits 128 VGPR + 128 acc). vmcnt FIFO (issue order B4,A8,A8/tile):
// tile-entry outstanding = A16(t) = 16; +B4 -> 20; gate vmcnt(16) drains
// exactly B4(t). Compiler's precise per-dependency waits cover af/bf use
// (m97: near-optimal); no manual full drain anywhere in the loop.
// ============================================================================
#define BUF_B 32768   // per B buffer: 256 tok x 64 k x 2 B

#define STAGE_BQ(Q1, QN, K0)                                                       \
  do {                                                                             \
    _Pragma("unroll") for (int r_ = 0; r_ < 2; ++r_) {                             \
      const int lin_ = r_ * 64 + wid * 8 + l3;                                     \
      gld_lds16(gB + (size_t)((lin_ >> 5) * 64 + (QN) * 32 + (lin_ & 31)) * LDB_ + \
                    (K0) + ((l7 ^ l3) * 8),                                        \
                ldsb + (Q1) * BUF_B + (QN) * 16384 +                               \
                    (r_ * 64 + wid * 8) * 128);                                    \
    }                                                                              \
  } while (0)

#define READS_B(P)                                                                 \
  _Pragma("unroll") for (int n_ = 0; n_ < 4; ++n_)                                 \
    _Pragma("unroll") for (int k_ = 0; k_ < 2; ++k_)                               \
      bf[n_][k_] = *(const short8*)(ldsb + (P) * BUF_B +                           \
          (n_ >> 1) * 16384 + (wc * 32 + (n_ & 1) * 16 + lanem) * 128 +            \
          (((k_ * 4 + laneq) ^ swz) * 16));

#define LOAD_A8(DST, KB)                                                           \
  _Pragma("unroll") for (int mf_ = 0; mf_ < 8; ++mf_)                              \
    DST[mf_] = *(const short8*)(gAf + (size_t)(KB) * AKBSTRIDE + mf_ * 1024);

#define MFMA32(AFR, KK)                                                            \
  __builtin_amdgcn_s_setprio(1);                                                   \
  _Pragma("unroll") for (int m_ = 0; m_ < 8; ++m_)                                 \
    _Pragma("unroll") for (int n_ = 0; n_ < 4; ++n_)                               \
      acc[m_][n_] = __builtin_amdgcn_mfma_f32_16x16x32_bf16(                       \
          AFR[m_], bf[n_][KK], acc[m_][n_], 0, 0, 0);                              \
  __builtin_amdgcn_s_setprio(0);

#define GEMM_CORE(NT)                                                              \
  /* prologue: B(t0) then A(t0) — issue order pinned */                            \
  STAGE_BQ(0, 0, 0); STAGE_BQ(0, 1, 0);                                            \
  __builtin_amdgcn_sched_barrier(0);                                               \
  LOAD_A8(afk0, 0); LOAD_A8(afk1, 1);                                              \
  for (int kt = 0; kt < (NT); ++kt) {                                              \
    const int p_ = kt & 1, q_ = p_ ^ 1;                                            \
    asm volatile("s_waitcnt vmcnt(16)\n\ts_barrier" ::: "memory");                 \
    if (kt + 1 < (NT)) { STAGE_BQ(q_, 0, (kt + 1) * 64);                           \
                         STAGE_BQ(q_, 1, (kt + 1) * 64); }                         \
    __builtin_amdgcn_sched_barrier(0);                                             \
    READS_B(p_);                                                                   \
    MFMA32(afk0, 0);                                                               \
    if (kt + 1 < (NT)) LOAD_A8(afk0, 2 * (kt + 1));                                \
    MFMA32(afk1, 1);                                                               \
    if (kt + 1 < (NT)) LOAD_A8(afk1, 2 * (kt + 1) + 1);                            \
  }

// ---------------- GEMM 1: Hs[tok][e*F+f] = bf16( gelu(x @ W1[e] + b1[e]) * r[tok,e] )
// Grid: 1024 blocks = e(8) x fb(2) x strip(64); strip fastest -> the 16 blocks
// sharing a token strip are 64 apart (same XCD); (e,fb) weight slice adjacent.
__global__ __launch_bounds__(512, 2) void gemm_h_kernel(
    const __hip_bfloat16* __restrict__ A, const __hip_bfloat16* __restrict__ W1f,
    const float* __restrict__ b1, const float* __restrict__ r,
    __hip_bfloat16* __restrict__ Hs) {
  const int bid = blockIdx.x;
  const int strip = bid & 63, fb = (bid >> 6) & 1, e = bid >> 7;
  const int T0 = strip * 256, F0 = fb * 256;

  __shared__ char ldsb[2 * BUF_B];   // 64 KiB (B only)

  const int tid = threadIdx.x, lane = tid & 63, wid = tid >> 6;
  const int wr = wid >> 2, wc = wid & 3;       // 2 x 4 wave grid
  const int lanem = lane & 15, laneq = lane >> 4;
  const int l3 = lane >> 3, l7 = lane & 7;     // staging lane decompose
  const int swz = lanem & 7;
  const int LDB_ = DDIM;
  const size_t AKBSTRIDE = 32 * 1024;          // bytes per kb step (32 mf frags)

  const __hip_bfloat16* gB = A + (size_t)T0 * DDIM;
  const char* gAf = (const char*)W1f + ((size_t)e * 1024 +
                    (F0 >> 4) + wr * 8) * 1024 + (size_t)lane * 16;

  floatx4 acc[8][4];
#pragma unroll
  for (int i = 0; i < 8; ++i)
#pragma unroll
    for (int j = 0; j < 4; ++j) acc[i][j] = (floatx4){0.f, 0.f, 0.f, 0.f};
  short8 afk0[8], afk1[8], bf[4][2];

  GEMM_CORE(DDIM / 64);

  // epilogue: bias -> fast exact-gelu -> router scale -> packed bf16x4 store
#pragma unroll
  for (int nj = 0; nj < 4; ++nj) {
    const int tok = T0 + wc * 64 + nj * 16 + lanem;
    const float rv = r[(size_t)tok * EEXP + e];
#pragma unroll
    for (int mi = 0; mi < 8; ++mi) {
      const int f = F0 + wr * 128 + mi * 16 + laneq * 4;   // 4 consecutive f
      const float4 b4 = *(const float4*)(b1 + e * FDIM + f);
      union { ushort4 u; __hip_bfloat16 h[4]; } pk;
      pk.h[0] = __float2bfloat16(gelu_fast(acc[mi][nj][0] + b4.x) * rv);
      pk.h[1] = __float2bfloat16(gelu_fast(acc[mi][nj][1] + b4.y) * rv);
      pk.h[2] = __float2bfloat16(gelu_fast(acc[mi][nj][2] + b4.z) * rv);
      pk.h[3] = __float2bfloat16(gelu_fast(acc[mi][nj][3] + b4.w) * rv);
      *(ushort4*)(Hs + (size_t)tok * EFK + e * FDIM + f) = pk.u;
    }
  }
}

// ---------------- GEMM 2: out[tok][d] = Hs[tok,:] @ W2flat[:,d] + sum_e r[tok,e]*b2[e,d]
// Grid: 256 blocks; the 4 d-quarter blocks of one token strip share an XCD
// (bid%8 == strip%8) -> strip's Hs rows L2-shared 4x (R1-verified: FETCH 115 MB).
__global__ __launch_bounds__(512, 2) void gemm_out_kernel(
    const __hip_bfloat16* __restrict__ Hs, const __hip_bfloat16* __restrict__ W2f,
    const float* __restrict__ b2, const float* __restrict__ r,
    float* __restrict__ out) {
  const int bid = blockIdx.x;
  const int strip = (bid >> 5) * 8 + (bid & 7);   // 0..63 token strip
  const int dq = (bid >> 3) & 3;                  // d quarter
  const int T0 = strip * 256, D0 = dq * 256;

  __shared__ char ldsb[2 * BUF_B];   // 64 KiB (B only)

  const int tid = threadIdx.x, lane = tid & 63, wid = tid >> 6;
  const int wr = wid >> 2, wc = wid & 3;
  const int lanem = lane & 15, laneq = lane >> 4;
  const int l3 = lane >> 3, l7 = lane & 7;
  const int swz = lanem & 7;
  const int LDB_ = EFK;
  const size_t AKBSTRIDE = 64 * 1024;             // bytes per kb step (64 mf frags)

  const __hip_bfloat16* gB = Hs + (size_t)T0 * EFK;
  const char* gAf = (const char*)W2f + ((size_t)(D0 >> 4) + wr * 8) * 1024 +
                    (size_t)lane * 16;

  floatx4 acc[8][4];
#pragma unroll
  for (int i = 0; i < 8; ++i)
#pragma unroll
    for (int j = 0; j < 4; ++j) acc[i][j] = (floatx4){0.f, 0.f, 0.f, 0.f};
  short8 afk0[8], afk1[8], bf[4][2];

  GEMM_CORE(EFK / 64);

  // epilogue: combined bias sum_e r[tok,e]*b2[e,d], float4 store
#pragma unroll
  for (int mi = 0; mi < 8; ++mi) {
    const int d0 = D0 + wr * 128 + mi * 16 + laneq * 4;    // 4 consecutive d
    float4 b2v[EEXP];
#pragma unroll
    for (int e = 0; e < EEXP; ++e) b2v[e] = *(const float4*)(b2 + e * DDIM + d0);
#pragma unroll
    for (int nj = 0; nj < 4; ++nj) {
      const int tok = T0 + wc * 64 + nj * 16 + lanem;
      const float4* r4 = (const float4*)(r + (size_t)tok * EEXP);
      const float4 r0 = r4[0], r1 = r4[1];
      const float rv[EEXP] = {r0.x, r0.y, r0.z, r0.w, r1.x, r1.y, r1.z, r1.w};
      float bx = 0.f, by = 0.f, bz = 0.f, bw = 0.f;
#pragma unroll
      for (int e = 0; e < EEXP; ++e) {
        bx += rv[e] * b2v[e].x; by += rv[e] * b2v[e].y;
        bz += rv[e] * b2v[e].z; bw += rv[e] * b2v[e].w;
      }
      float4 o;
      o.x = acc[mi][nj][0] + bx; o.y = acc[mi][nj][1] + by;
      o.z = acc[mi][nj][2] + bz; o.w = acc[mi][nj][3] + bw;
      *(float4*)(out + (size_t)tok * DDIM + d0) = o;
    }
  }
}

extern "C" void kernel_launch(void* const* d_in, const int* in_sizes, int n_in,
                              void* d_out, int out_size, void* d_ws, size_t ws_size,
                              hipStream_t stream) {
  const float* x  = (const float*)d_in[0];
  const float* W1 = (const float*)d_in[1];
  const float* b1 = (const float*)d_in[2];
  const float* W2 = (const float*)d_in[3];
  const float* b2 = (const float*)d_in[4];
  const float* Wr = (const float*)d_in[5];
  const float* br = (const float*)d_in[6];
  float* out = (float*)d_out;

  char* ws = (char*)d_ws;
  __hip_bfloat16* xbf = (__hip_bfloat16*)(ws);                            // 32 MB
  __hip_bfloat16* W1f = (__hip_bfloat16*)(ws + (32u << 20));              // 8 MB  frag-order
  __hip_bfloat16* W2f = (__hip_bfloat16*)(ws + (40u << 20));              // 8 MB  frag-order
  float*          r   = (float*)(ws + (48u << 20));                       // 0.5 MB [MTOK][E]
  __hip_bfloat16* Hs  = (__hip_bfloat16*)(ws + (48u << 20) + (1u << 19)); // 128 MB [MTOK][E*F]

  // W1 [E][D][F] -> MFMA-fragment order (one wave per 1 KiB frag)
  frag_cast_w1<<<2048, 256, 0, stream>>>(W1, W1f);
  // W2 [E*F][D] -> MFMA-fragment order
  frag_cast_w2<<<2048, 256, 0, stream>>>(W2, W2f);
  // router softmax + x cast
  router_cast_kernel<<<MTOK / 4, 256, 0, stream>>>(x, Wr, br, xbf, r);
  // stage 1 grouped GEMM (+gelu, +router scale): 256-f x 256-tok tiles
  gemm_h_kernel<<<dim3((MTOK / 256) * (FDIM / 256) * EEXP), 512, 0, stream>>>(xbf, W1f, b1, r, Hs);
  // stage 2 GEMM (+combined bias): 256-d x 256-tok tiles, XCD-grouped strips
  gemm_out_kernel<<<dim3((MTOK / 256) * (DDIM / 256)), 512, 0, stream>>>(Hs, W2f, b2, r, out);
}